// Round 7
// baseline (47.735 us; speedup 1.0000x reference)
//
#include <hip/hip_runtime.h>

// Deimv2LQE: out = scores + MLP(top4-softmax-stats(pred_corners))
// 262144 rows; per row 132 f32 (4 corners x 33 bins).
// R7: TWO-KERNEL SPLIT for max TLP per phase.
//   K1 lqe_stats: 1 wave per 16 rows (16384 waves, 4x R6): per lane one
//     (row,corner) task, direct gather loads (proven best in R6), ~700 cyc
//     compute, writes 5 stats to TRANSPOSED planes in d_ws
//     (stat[k][row], k=corner*5+i) so K2 reads coalesce.
//   K2 lqe_mlp: lane-per-row, 20 coalesced plane loads prefetched, then the
//     pure-register 20->64->1 MLP with wave-uniform s_load weights.
//   Fallback to the fused R6 kernel if ws_size < 21 MB.

#define THREADS 256

typedef float f32x4 __attribute__((ext_vector_type(4), aligned(4)));

// branchless top4 + softmax stats for one 33-bin corner held in x[]
__device__ __forceinline__ void corner_stats(const float x[33],
                                             float& p0, float& p1, float& p2,
                                             float& p3, float& pm)
{
    float t0 = x[0], t1 = x[1], t2 = x[2], t3 = x[3];
    float a;
    a = fmaxf(t0, t1); t1 = fminf(t0, t1); t0 = a;
    a = fmaxf(t2, t3); t3 = fminf(t2, t3); t2 = a;
    a = fmaxf(t0, t2); t2 = fminf(t0, t2); t0 = a;
    a = fmaxf(t1, t3); t3 = fminf(t1, t3); t1 = a;
    a = fmaxf(t1, t2); t2 = fminf(t1, t2); t1 = a;
    #pragma unroll
    for (int k = 4; k < 33; ++k) {
        float xx = x[k];
        a = fmaxf(t0, xx); xx = fminf(t0, xx); t0 = a;
        a = fmaxf(t1, xx); xx = fminf(t1, xx); t1 = a;
        a = fmaxf(t2, xx); xx = fminf(t2, xx); t2 = a;
        t3 = fmaxf(t3, xx);
    }
    float ssum = 0.f;
    #pragma unroll
    for (int k = 0; k < 33; ++k) ssum += __expf(x[k] - t0);
    const float inv = 1.0f / ssum;
    p0 = inv;
    p1 = __expf(t1 - t0) * inv;
    p2 = __expf(t2 - t0) * inv;
    p3 = __expf(t3 - t0) * inv;
    pm = 0.25f * (p0 + p1 + p2 + p3);
}

// ---------------- K1: stats (1 wave = 16 rows x 4 corners) ----------------
__global__ __launch_bounds__(THREADS)
void lqe_stats(const float* __restrict__ pc, float* __restrict__ stats,
               int nrows)
{
    const int tid = threadIdx.x;
    const int l = tid & 63;
    const int rowBase = blockIdx.x * 64 + (tid >> 6) * 16;
    const int r = rowBase + (l >> 2);
    const int c = l & 3;

    const float* base = pc + (long long)r * 132 + c * 33;
    float x[33];
    #pragma unroll
    for (int i = 0; i < 8; ++i) {
        f32x4 v = *(const f32x4*)(base + i * 4);
        x[4*i+0] = v.x; x[4*i+1] = v.y; x[4*i+2] = v.z; x[4*i+3] = v.w;
    }
    x[32] = base[32];

    float p0, p1, p2, p3, pm;
    corner_stats(x, p0, p1, p2, p3, pm);

    float* sp = stats + (size_t)c * 5 * nrows + r;
    sp[0]                  = p0;
    sp[(size_t)nrows]      = p1;
    sp[(size_t)nrows * 2]  = p2;
    sp[(size_t)nrows * 3]  = p3;
    sp[(size_t)nrows * 4]  = pm;
}

// ---------------- K2: MLP (lane-per-row, coalesced stat reads) -------------
__global__ __launch_bounds__(THREADS)
void lqe_mlp(const float* __restrict__ scores, const float* __restrict__ stats,
             const float* __restrict__ w1, const float* __restrict__ b1,
             const float* __restrict__ w2, const float* __restrict__ b2,
             float* __restrict__ out, int nrows)
{
    const int r = blockIdx.x * THREADS + threadIdx.x;

    float st[20];
    #pragma unroll
    for (int k = 0; k < 20; ++k) st[k] = stats[(size_t)k * nrows + r];
    const float sc = scores[r];

    float acc = 0.f;
    #pragma unroll
    for (int jc = 0; jc < 4; ++jc) {
        float h[16];
        #pragma unroll
        for (int j = 0; j < 16; ++j) h[j] = b1[jc * 16 + j];
        #pragma unroll
        for (int k = 0; k < 20; ++k) {
            #pragma unroll
            for (int j = 0; j < 16; ++j)
                h[j] = fmaf(st[k], w1[k * 64 + jc * 16 + j], h[j]);
        }
        #pragma unroll
        for (int j = 0; j < 16; ++j)
            acc = fmaf(fmaxf(h[j], 0.f), w2[jc * 16 + j], acc);
    }

    out[r] = sc + acc + b2[0];
}

// ---------------- fallback: fused R6 kernel (ws too small) -----------------
__global__ __launch_bounds__(THREADS, 4)
void lqe_fused(const float* __restrict__ scores, const float* __restrict__ pc,
               const float* __restrict__ w1, const float* __restrict__ b1,
               const float* __restrict__ w2, const float* __restrict__ b2,
               float* __restrict__ out)
{
    __shared__ float sm_stat[4][64 * 21];
    const int tid = threadIdx.x;
    const int wv = tid >> 6, l = tid & 63;
    float* const statS = sm_stat[wv];
    const long long waveRowBase = (long long)blockIdx.x * 256 + wv * 64;
    const float myScore = scores[waveRowBase + l];

    #pragma unroll
    for (int s = 0; s < 4; ++s) {
        const float* base =
            pc + (waveRowBase + s * 16 + (l >> 2)) * 132 + (l & 3) * 33;
        float x[33];
        #pragma unroll
        for (int i = 0; i < 8; ++i) {
            f32x4 v = *(const f32x4*)(base + i * 4);
            x[4*i+0] = v.x; x[4*i+1] = v.y; x[4*i+2] = v.z; x[4*i+3] = v.w;
        }
        x[32] = base[32];
        float p0, p1, p2, p3, pm;
        corner_stats(x, p0, p1, p2, p3, pm);
        float* sd = statS + (s * 16 + (l >> 2)) * 21 + (l & 3) * 5;
        sd[0] = p0; sd[1] = p1; sd[2] = p2; sd[3] = p3; sd[4] = pm;
    }

    float st[20];
    #pragma unroll
    for (int k = 0; k < 20; ++k) st[k] = statS[l * 21 + k];
    float acc = 0.f;
    #pragma unroll
    for (int jc = 0; jc < 4; ++jc) {
        float h[16];
        #pragma unroll
        for (int j = 0; j < 16; ++j) h[j] = b1[jc * 16 + j];
        #pragma unroll
        for (int k = 0; k < 20; ++k) {
            #pragma unroll
            for (int j = 0; j < 16; ++j)
                h[j] = fmaf(st[k], w1[k * 64 + jc * 16 + j], h[j]);
        }
        #pragma unroll
        for (int j = 0; j < 16; ++j)
            acc = fmaf(fmaxf(h[j], 0.f), w2[jc * 16 + j], acc);
    }
    out[waveRowBase + l] = myScore + acc + b2[0];
}

extern "C" void kernel_launch(void* const* d_in, const int* in_sizes, int n_in,
                              void* d_out, int out_size, void* d_ws, size_t ws_size,
                              hipStream_t stream) {
    const float* scores = (const float*)d_in[0];
    const float* pc     = (const float*)d_in[1];
    const float* w1     = (const float*)d_in[2];
    const float* b1     = (const float*)d_in[3];
    const float* w2     = (const float*)d_in[4];
    const float* b2     = (const float*)d_in[5];
    float* out = (float*)d_out;

    const int rows = out_size;                       // 262144
    const size_t need = (size_t)rows * 20 * sizeof(float);

    if (ws_size >= need) {
        float* stats = (float*)d_ws;
        lqe_stats<<<rows / 64, THREADS, 0, stream>>>(pc, stats, rows);
        lqe_mlp<<<rows / THREADS, THREADS, 0, stream>>>(scores, stats, w1, b1,
                                                        w2, b2, out, rows);
    } else {
        lqe_fused<<<rows / 256, THREADS, 0, stream>>>(scores, pc, w1, b1,
                                                      w2, b2, out);
    }
}

// Round 8
// 40.227 us; speedup vs baseline: 1.1866x; 1.1866x over previous
//
#include <hip/hip_runtime.h>

// Deimv2LQE: out = scores + MLP(top4-softmax-stats(pred_corners))
// 262144 rows; per row 132 f32 (4 corners x 33 bins).
// R8 = R6 shell (direct gather, 4-wave blocks, barrier-free, lane-per-row
//     MLP with wave-uniform s_load weights) + ILP RESTRUCTURE of the compute:
//     - top-4 via 4 independent groups (ILP=4) + log-depth bitonic merges
//       (previous: single dependent insert chain, ~460-cyc critical path ->
//        ~150 cyc; VALUBusy was pinned at 25% in ALL 7 prior rounds = the
//        signature of one ready wave running a dependent chain)
//     - exp-sum with 4 accumulators (chain 33 -> 9)
//     - MLP output with 4 accumulators (chain 64 -> 16)

#define THREADS 256

typedef float f32x4 __attribute__((ext_vector_type(4), aligned(4)));

__device__ __forceinline__ void sort4d(float& a, float& b, float& c, float& d) {
    float t;
    t = fmaxf(a, b); b = fminf(a, b); a = t;
    t = fmaxf(c, d); d = fminf(c, d); c = t;
    t = fmaxf(a, c); c = fminf(a, c); a = t;
    t = fmaxf(b, d); d = fminf(b, d); b = t;
    t = fmaxf(b, c); c = fminf(b, c); b = t;
}
__device__ __forceinline__ void ins4(float& a, float& b, float& c, float& d,
                                     float x) {
    float t;
    t = fmaxf(a, x); x = fminf(a, x); a = t;
    t = fmaxf(b, x); x = fminf(b, x); b = t;
    t = fmaxf(c, x); x = fminf(c, x); c = t;
    d = fmaxf(d, x);
}
// top-4 of two descending quads -> descending quad in (a0..a3)
__device__ __forceinline__ void merge4(float& a0, float& a1, float& a2,
                                       float& a3, float b0, float b1,
                                       float b2, float b3) {
    a0 = fmaxf(a0, b3);
    a1 = fmaxf(a1, b2);
    a2 = fmaxf(a2, b1);
    a3 = fmaxf(a3, b0);
    sort4d(a0, a1, a2, a3);
}

__global__ __launch_bounds__(THREADS, 4)
void lqe_kernel(const float* __restrict__ scores,
                const float* __restrict__ pc,
                const float* __restrict__ w1,
                const float* __restrict__ b1,
                const float* __restrict__ w2,
                const float* __restrict__ b2,
                float* __restrict__ out)
{
    __shared__ float sm_stat[4][64 * 21];   // per-wave slices, stride 21 (odd)

    const int tid = threadIdx.x;
    const int wv = tid >> 6;
    const int l  = tid & 63;
    float* const statS = sm_stat[wv];

    const long long waveRowBase = (long long)blockIdx.x * 256 + wv * 64;
    const float myScore = scores[waveRowBase + l];

    // ---- corner phase: 4 substages x (16 rows x 4 corners = 64 tasks) ----
    #pragma unroll
    for (int s = 0; s < 4; ++s) {
        const float* base =
            pc + (waveRowBase + s * 16 + (l >> 2)) * 132 + (l & 3) * 33;

        float x[33];
        #pragma unroll
        for (int i = 0; i < 8; ++i) {
            f32x4 v = *(const f32x4*)(base + i * 4);
            x[4*i+0] = v.x; x[4*i+1] = v.y; x[4*i+2] = v.z; x[4*i+3] = v.w;
        }
        x[32] = base[32];

        // ---- top-4: 4 independent groups (ILP=4), then bitonic merges ----
        float a0 = x[0],  a1 = x[1],  a2 = x[2],  a3 = x[3];
        float c0 = x[8],  c1 = x[9],  c2 = x[10], c3 = x[11];
        float d0 = x[16], d1 = x[17], d2 = x[18], d3 = x[19];
        float e0 = x[24], e1 = x[25], e2 = x[26], e3 = x[27];
        sort4d(a0, a1, a2, a3);
        sort4d(c0, c1, c2, c3);
        sort4d(d0, d1, d2, d3);
        sort4d(e0, e1, e2, e3);
        #pragma unroll
        for (int k = 0; k < 4; ++k) {
            ins4(a0, a1, a2, a3, x[4 + k]);
            ins4(c0, c1, c2, c3, x[12 + k]);
            ins4(d0, d1, d2, d3, x[20 + k]);
            ins4(e0, e1, e2, e3, x[28 + k]);
        }
        ins4(e0, e1, e2, e3, x[32]);
        merge4(a0, a1, a2, a3, c0, c1, c2, c3);
        merge4(d0, d1, d2, d3, e0, e1, e2, e3);
        merge4(a0, a1, a2, a3, d0, d1, d2, d3);
        const float t0 = a0, t1 = a1, t2 = a2, t3 = a3;

        // ---- softmax denom: 4 accumulators (chain 33 -> 9) ----
        float sa = 0.f, sb = 0.f, sc = 0.f, sd = 0.f;
        #pragma unroll
        for (int k = 0; k < 32; k += 4) {
            sa += __expf(x[k + 0] - t0);
            sb += __expf(x[k + 1] - t0);
            sc += __expf(x[k + 2] - t0);
            sd += __expf(x[k + 3] - t0);
        }
        sa += __expf(x[32] - t0);
        const float inv = 1.0f / ((sa + sb) + (sc + sd));
        const float p0 = inv;
        const float p1 = __expf(t1 - t0) * inv;
        const float p2 = __expf(t2 - t0) * inv;
        const float p3 = __expf(t3 - t0) * inv;
        const float pm = 0.25f * (p0 + p1 + p2 + p3);

        float* sd_ = statS + (s * 16 + (l >> 2)) * 21 + (l & 3) * 5;
        sd_[0] = p0; sd_[1] = p1; sd_[2] = p2; sd_[3] = p3; sd_[4] = pm;
    }

    // ---- MLP: lane-per-row within the wave's private slice ----
    float st[20];
    #pragma unroll
    for (int k = 0; k < 20; ++k) st[k] = statS[l * 21 + k];

    float acc0 = 0.f, acc1 = 0.f, acc2 = 0.f, acc3 = 0.f;
    #pragma unroll
    for (int jc = 0; jc < 4; ++jc) {
        float h[16];
        #pragma unroll
        for (int j = 0; j < 16; ++j) h[j] = b1[jc * 16 + j];
        #pragma unroll
        for (int k = 0; k < 20; ++k) {
            #pragma unroll
            for (int j = 0; j < 16; ++j)
                h[j] = fmaf(st[k], w1[k * 64 + jc * 16 + j], h[j]);
        }
        #pragma unroll
        for (int j = 0; j < 16; j += 4) {
            acc0 = fmaf(fmaxf(h[j + 0], 0.f), w2[jc * 16 + j + 0], acc0);
            acc1 = fmaf(fmaxf(h[j + 1], 0.f), w2[jc * 16 + j + 1], acc1);
            acc2 = fmaf(fmaxf(h[j + 2], 0.f), w2[jc * 16 + j + 2], acc2);
            acc3 = fmaf(fmaxf(h[j + 3], 0.f), w2[jc * 16 + j + 3], acc3);
        }
    }

    out[waveRowBase + l] = myScore + ((acc0 + acc1) + (acc2 + acc3)) + b2[0];
}

extern "C" void kernel_launch(void* const* d_in, const int* in_sizes, int n_in,
                              void* d_out, int out_size, void* d_ws, size_t ws_size,
                              hipStream_t stream) {
    const float* scores = (const float*)d_in[0];
    const float* pc     = (const float*)d_in[1];
    const float* w1     = (const float*)d_in[2];
    const float* b1     = (const float*)d_in[3];
    const float* w2     = (const float*)d_in[4];
    const float* b2     = (const float*)d_in[5];
    float* out = (float*)d_out;

    const int rows = out_size;            // 262144
    const int blocks = rows / 256;        // 1024
    lqe_kernel<<<blocks, THREADS, 0, stream>>>(scores, pc, w1, b1, w2, b2, out);
}

// Round 9
// 32.664 us; speedup vs baseline: 1.4614x; 1.2316x over previous
//
#include <hip/hip_runtime.h>

// Deimv2LQE: out = scores + MLP(top4-softmax-stats(pred_corners))
// 262144 rows; per row 132 f32 (4 corners x 33 bins).
// R9: line-optimal memory path. Block = 256 threads = 64 rows, grid 4096.
//   - stage 64 rows (8448 f) as 8x float4/thread, PERFECTLY contiguous:
//     16 lines/instruction (R6/R8's gather spanned ~64 lines/instr -> 4x
//     TA/L1 line-service cost + L1-evict refetches; theory: that was the
//     invariant ~40us wall)
//   - corner compute = R8's ILP version (grouped top-4 + bitonic merge)
//   - wave-split MLP: wave wv computes hidden slice [16wv,16wv+16) for all
//     64 rows (lane=row); wv readfirstlane'd -> weight idx scalar (s_load).
//     Partials reduced via LDS by wave 0. 3 barriers/block, blocks short.

#define THREADS 256
#define ROWS 64

typedef float f32x4 __attribute__((ext_vector_type(4), aligned(16)));

__device__ __forceinline__ void sort4d(float& a, float& b, float& c, float& d) {
    float t;
    t = fmaxf(a, b); b = fminf(a, b); a = t;
    t = fmaxf(c, d); d = fminf(c, d); c = t;
    t = fmaxf(a, c); c = fminf(a, c); a = t;
    t = fmaxf(b, d); d = fminf(b, d); b = t;
    t = fmaxf(b, c); c = fminf(b, c); b = t;
}
__device__ __forceinline__ void ins4(float& a, float& b, float& c, float& d,
                                     float x) {
    float t;
    t = fmaxf(a, x); x = fminf(a, x); a = t;
    t = fmaxf(b, x); x = fminf(b, x); b = t;
    t = fmaxf(c, x); x = fminf(c, x); c = t;
    d = fmaxf(d, x);
}
__device__ __forceinline__ void merge4(float& a0, float& a1, float& a2,
                                       float& a3, float b0, float b1,
                                       float b2, float b3) {
    a0 = fmaxf(a0, b3);
    a1 = fmaxf(a1, b2);
    a2 = fmaxf(a2, b1);
    a3 = fmaxf(a3, b0);
    sort4d(a0, a1, a2, a3);
}

__global__ __launch_bounds__(THREADS, 4)
void lqe_kernel(const float* __restrict__ scores,
                const float* __restrict__ pc,
                const float* __restrict__ w1,
                const float* __restrict__ b1,
                const float* __restrict__ w2,
                const float* __restrict__ b2,
                float* __restrict__ out)
{
    __shared__ float sm_stage[ROWS * 132];  // 33792 B; reused for partials
    __shared__ float sm_stat[ROWS * 21];    // 5376 B, stride 21 (odd)

    const int t = threadIdx.x;
    const long long rowBase = (long long)blockIdx.x * ROWS;

    // ---- stage: 2112 float4, fully contiguous & coalesced ----
    {
        const f32x4* __restrict__ src = (const f32x4*)(pc + rowBase * 132);
        f32x4* dst = (f32x4*)sm_stage;
        #pragma unroll
        for (int i = 0; i < 8; ++i) dst[t + i * 256] = src[t + i * 256];
        if (t < 64) dst[2048 + t] = src[2048 + t];
    }
    __syncthreads();

    // ---- corner task t: row = t>>2, corner = t&3; LDS base 33*t ----
    {
        const float* v = sm_stage + t * 33;
        float x[33];
        #pragma unroll
        for (int k = 0; k < 33; ++k) x[k] = v[k];

        float a0 = x[0],  a1 = x[1],  a2 = x[2],  a3 = x[3];
        float c0 = x[8],  c1 = x[9],  c2 = x[10], c3 = x[11];
        float d0 = x[16], d1 = x[17], d2 = x[18], d3 = x[19];
        float e0 = x[24], e1 = x[25], e2 = x[26], e3 = x[27];
        sort4d(a0, a1, a2, a3);
        sort4d(c0, c1, c2, c3);
        sort4d(d0, d1, d2, d3);
        sort4d(e0, e1, e2, e3);
        #pragma unroll
        for (int k = 0; k < 4; ++k) {
            ins4(a0, a1, a2, a3, x[4 + k]);
            ins4(c0, c1, c2, c3, x[12 + k]);
            ins4(d0, d1, d2, d3, x[20 + k]);
            ins4(e0, e1, e2, e3, x[28 + k]);
        }
        ins4(e0, e1, e2, e3, x[32]);
        merge4(a0, a1, a2, a3, c0, c1, c2, c3);
        merge4(d0, d1, d2, d3, e0, e1, e2, e3);
        merge4(a0, a1, a2, a3, d0, d1, d2, d3);
        const float t0 = a0, t1 = a1, t2 = a2, t3 = a3;

        float sa = 0.f, sb = 0.f, sc = 0.f, sd = 0.f;
        #pragma unroll
        for (int k = 0; k < 32; k += 4) {
            sa += __expf(x[k + 0] - t0);
            sb += __expf(x[k + 1] - t0);
            sc += __expf(x[k + 2] - t0);
            sd += __expf(x[k + 3] - t0);
        }
        sa += __expf(x[32] - t0);
        const float inv = 1.0f / ((sa + sb) + (sc + sd));
        const float p0 = inv;
        const float p1 = __expf(t1 - t0) * inv;
        const float p2 = __expf(t2 - t0) * inv;
        const float p3 = __expf(t3 - t0) * inv;
        const float pm = 0.25f * (p0 + p1 + p2 + p3);

        float* sd_ = sm_stat + (t >> 2) * 21 + (t & 3) * 5;
        sd_[0] = p0; sd_[1] = p1; sd_[2] = p2; sd_[3] = p3; sd_[4] = pm;
    }
    __syncthreads();

    // ---- MLP: wave wv computes hidden slice [16wv,16wv+16) for row l ----
    {
        const int l  = t & 63;
        const int wv = __builtin_amdgcn_readfirstlane(t >> 6);  // scalar
        const float* __restrict__ w1s = w1 + wv * 16;   // scalar base
        const float* __restrict__ w2s = w2 + wv * 16;
        const float* __restrict__ b1s = b1 + wv * 16;

        float st[20];
        #pragma unroll
        for (int k = 0; k < 20; ++k) st[k] = sm_stat[l * 21 + k];

        float h[16];
        #pragma unroll
        for (int j = 0; j < 16; ++j) h[j] = b1s[j];
        #pragma unroll
        for (int k = 0; k < 20; ++k) {
            #pragma unroll
            for (int j = 0; j < 16; ++j)
                h[j] = fmaf(st[k], w1s[k * 64 + j], h[j]);
        }
        float acc0 = 0.f, acc1 = 0.f, acc2 = 0.f, acc3 = 0.f;
        #pragma unroll
        for (int j = 0; j < 16; j += 4) {
            acc0 = fmaf(fmaxf(h[j + 0], 0.f), w2s[j + 0], acc0);
            acc1 = fmaf(fmaxf(h[j + 1], 0.f), w2s[j + 1], acc1);
            acc2 = fmaf(fmaxf(h[j + 2], 0.f), w2s[j + 2], acc2);
            acc3 = fmaf(fmaxf(h[j + 3], 0.f), w2s[j + 3], acc3);
        }
        // partials into the (now dead) stage region
        sm_stage[wv * 64 + l] = (acc0 + acc1) + (acc2 + acc3);
    }
    __syncthreads();

    // ---- wave 0: reduce 4 partials, add score, coalesced store ----
    if (t < 64) {
        const float r = (sm_stage[t] + sm_stage[64 + t]) +
                        (sm_stage[128 + t] + sm_stage[192 + t]);
        out[rowBase + t] = scores[rowBase + t] + r + b2[0];
    }
}

extern "C" void kernel_launch(void* const* d_in, const int* in_sizes, int n_in,
                              void* d_out, int out_size, void* d_ws, size_t ws_size,
                              hipStream_t stream) {
    const float* scores = (const float*)d_in[0];
    const float* pc     = (const float*)d_in[1];
    const float* w1     = (const float*)d_in[2];
    const float* b1     = (const float*)d_in[3];
    const float* w2     = (const float*)d_in[4];
    const float* b2     = (const float*)d_in[5];
    float* out = (float*)d_out;

    const int rows = out_size;          // 262144
    const int blocks = rows / ROWS;     // 4096
    lqe_kernel<<<blocks, THREADS, 0, stream>>>(scores, pc, w1, b1, w2, b2, out);
}